// Round 5
// baseline (248.005 us; speedup 1.0000x reference)
//
#include <hip/hip_runtime.h>

#define NEGV (-1.0e9f)

typedef __bf16 bf16_t;
typedef __bf16 bf16x8 __attribute__((ext_vector_type(8)));
typedef __bf16 bf16x4 __attribute__((ext_vector_type(4)));
typedef float  f32x4  __attribute__((ext_vector_type(4)));

// async global->LDS, 16B per lane; LDS dest is wave-uniform base + lane*16
__device__ __forceinline__ void gld16(const void* g, void* l) {
    __builtin_amdgcn_global_load_lds(
        (const __attribute__((address_space(1))) void*)g,
        (__attribute__((address_space(3))) void*)l, 16, 0, 0);
}

// ===========================================================================
// Triple-buffered counted-vmcnt mainloops (T3+T4), BK=32, with the m201
// PHASE RHYTHM: small {ds_read burst + 1 stage half -> barrier -> lgkm0 ->
// setprio(1) + 16 MFMA + setprio(0) -> barrier} phases so the LDS pipe and
// the matrix pipe overlap across waves (r4's one-big-burst-per-tile
// serialized them: ~1100cy LDS then ~1229cy MFMA per tile, 30% MfmaUtil).
//
// LDS layout per operand tile: row r (64B) at byte r*64; 16B chunk p of row
// r holds logical k-chunk p ^ ((r>>1)&3).  ds_read_b128 fragment reads land
// 2-way on banks (free, m136); staged with LINEAR LDS dest (gld16
// requirement) + inverse-swizzled GLOBAL source.  Measured 0 conflicts.
//
// Staging: tile kt+2 staged during tile kt (buffer (kt+2)%3, 2 buffers away
// from the read buffer -> race-free); boundary wait = vmcnt(4)/(3): retires
// tile kt+1's loads, leaves tile kt+2's IN FLIGHT across the barrier.
// ===========================================================================

#define MMR(AF, IB)                                                                        \
    acc[IB][0] = __builtin_amdgcn_mfma_f32_16x16x32_bf16(AF, b0, acc[IB][0], 0, 0, 0);     \
    acc[IB][1] = __builtin_amdgcn_mfma_f32_16x16x32_bf16(AF, b1, acc[IB][1], 0, 0, 0);     \
    acc[IB][2] = __builtin_amdgcn_mfma_f32_16x16x32_bf16(AF, b2, acc[IB][2], 0, 0, 0);     \
    acc[IB][3] = __builtin_amdgcn_mfma_f32_16x16x32_bf16(AF, b3, acc[IB][3], 0, 0, 0)

// ---- 256x256 tile, 8 waves (2M x 4N), acc[8][4], LDS 3 x 32K = 96 KiB ----
__device__ __forceinline__ void ml256x256(
    const bf16_t* __restrict__ A, const bf16_t* __restrict__ B,
    int ldA, int ldB, int nkt, char* smem, int tid, f32x4 acc[8][4])
{
    const int w = tid >> 6, lane = tid & 63;
    const int wm = w & 1, wn = w >> 1;
    const int l16 = lane & 15, quad = lane >> 4;

    // staging: slot s=u*512+tid -> LDS byte s*16; global row s>>2,
    // chunk (s&3)^((s>>3)&3)
    const int g0 = 2 * (tid >> 3) + ((tid >> 2) & 1);
    const int c0 = ((tid & 3) ^ ((tid >> 3) & 3)) * 8;
    const bf16_t* pa0 = A + (size_t)g0 * ldA + c0;
    const bf16_t* pa1 = pa0 + (size_t)128 * ldA;
    const bf16_t* pb0 = B + (size_t)g0 * ldB + c0;
    const bf16_t* pb1 = pb0 + (size_t)128 * ldB;
    char* const stA = smem + (w << 10);           // + u*8192 + buf*32768
    char* const stB = smem + 16384 + (w << 10);

    // fragment read: row R=base+l16: byte R*64 + ((quad^((l16>>1)&3))<<4)
    const int rowo = (l16 >> 1) * 128 + (l16 & 1) * 64 + ((quad ^ ((l16 >> 1) & 3)) << 4);
    const char* rdA = smem + (wm << 13) + rowo;            // + i*1024 + bufo
    const char* rdB = smem + 16384 + (wn << 12) + rowo;    // + j*1024 + bufo

#define STGA(BO) do { gld16(pa0, stA + (BO)); gld16(pa1, stA + (BO) + 8192);   \
                      pa0 += 32; pa1 += 32; } while (0)
#define STGB(BO) do { gld16(pb0, stB + (BO)); gld16(pb1, stB + (BO) + 8192);   \
                      pb0 += 32; pb1 += 32; } while (0)

    STGA(0); STGB(0);                          // tile 0 -> buf 0
    if (nkt > 1) {
        STGA(32768); STGB(32768);              // tile 1 -> buf 1
        asm volatile("s_waitcnt vmcnt(4)" ::: "memory");   // t0 done, t1 in flight
    } else {
        asm volatile("s_waitcnt vmcnt(0)" ::: "memory");
    }
    __builtin_amdgcn_s_barrier();

    int ro = 0, so = 65536;
    for (int kt = 0; kt < nkt; ++kt) {
        const char* ra = rdA + ro;
        const char* rb = rdB + ro;
        const bool st = (kt + 2) < nkt;
        // ---------- phase 1: 8 ds_read + A-stage | barrier | 16 MFMA ----------
        bf16x8 a0 = *(const bf16x8*)(ra);
        bf16x8 a1 = *(const bf16x8*)(ra + 1024);
        bf16x8 a2 = *(const bf16x8*)(ra + 2048);
        bf16x8 a3 = *(const bf16x8*)(ra + 3072);
        bf16x8 b0 = *(const bf16x8*)(rb);
        bf16x8 b1 = *(const bf16x8*)(rb + 1024);
        bf16x8 b2 = *(const bf16x8*)(rb + 2048);
        bf16x8 b3 = *(const bf16x8*)(rb + 3072);
        if (st) STGA(so);                      // stage tile kt+2, A half
        __builtin_amdgcn_s_barrier();
        asm volatile("s_waitcnt lgkmcnt(0)" ::: "memory");
        __builtin_amdgcn_sched_barrier(0);
        __builtin_amdgcn_s_setprio(1);
        MMR(a0, 0); MMR(a1, 1); MMR(a2, 2); MMR(a3, 3);
        __builtin_amdgcn_s_setprio(0);
        __builtin_amdgcn_s_barrier();
        // ---------- phase 2: 4 ds_read + B-stage | barrier | 16 MFMA ----------
        bf16x8 a4 = *(const bf16x8*)(ra + 4096);
        bf16x8 a5 = *(const bf16x8*)(ra + 5120);
        bf16x8 a6 = *(const bf16x8*)(ra + 6144);
        bf16x8 a7 = *(const bf16x8*)(ra + 7168);
        if (st) STGB(so);                      // stage tile kt+2, B half
        __builtin_amdgcn_s_barrier();
        asm volatile("s_waitcnt lgkmcnt(0)" ::: "memory");
        __builtin_amdgcn_sched_barrier(0);
        __builtin_amdgcn_s_setprio(1);
        MMR(a4, 4); MMR(a5, 5); MMR(a6, 6); MMR(a7, 7);
        __builtin_amdgcn_s_setprio(0);
        if (st) asm volatile("s_waitcnt vmcnt(4)" ::: "memory");  // t_{kt+1} done
        else    asm volatile("s_waitcnt vmcnt(0)" ::: "memory");
        __builtin_amdgcn_s_barrier();
        ro = (ro == 65536) ? 0 : (ro + 32768);
        so = (so == 65536) ? 0 : (so + 32768);
    }
#undef STGA
#undef STGB
}

// ---- 256x128 tile, 8 waves (4M x 2N), acc[4][4], LDS 3 x 24K = 72 KiB ----
__device__ __forceinline__ void ml256x128(
    const bf16_t* __restrict__ A, const bf16_t* __restrict__ B,
    int ldA, int ldB, int nkt, char* smem, int tid, f32x4 acc[4][4])
{
    const int w = tid >> 6, lane = tid & 63;
    const int wm = w & 3, wn = w >> 2;
    const int l16 = lane & 15, quad = lane >> 4;

    const int g0 = 2 * (tid >> 3) + ((tid >> 2) & 1);
    const int c0 = ((tid & 3) ^ ((tid >> 3) & 3)) * 8;
    const bf16_t* pa0 = A + (size_t)g0 * ldA + c0;
    const bf16_t* pa1 = pa0 + (size_t)128 * ldA;
    const bf16_t* pb0 = B + (size_t)g0 * ldB + c0;
    char* const stA = smem + (w << 10);
    char* const stB = smem + 16384 + (w << 10);

    const int rowo = (l16 >> 1) * 128 + (l16 & 1) * 64 + ((quad ^ ((l16 >> 1) & 3)) << 4);
    const char* rdA = smem + (wm << 12) + rowo;            // + i*1024 + bufo
    const char* rdB = smem + 16384 + (wn << 12) + rowo;    // + j*1024 + bufo

#define STG3(BO) do { gld16(pa0, stA + (BO)); gld16(pa1, stA + (BO) + 8192);   \
                      gld16(pb0, stB + (BO));                                  \
                      pa0 += 32; pa1 += 32; pb0 += 32; } while (0)

    STG3(0);
    if (nkt > 1) {
        STG3(24576);
        asm volatile("s_waitcnt vmcnt(3)" ::: "memory");
    } else {
        asm volatile("s_waitcnt vmcnt(0)" ::: "memory");
    }
    __builtin_amdgcn_s_barrier();

    int ro = 0, so = 49152;
    for (int kt = 0; kt < nkt; ++kt) {
        const char* ra = rdA + ro;
        const char* rb = rdB + ro;
        bf16x8 a0 = *(const bf16x8*)(ra);
        bf16x8 a1 = *(const bf16x8*)(ra + 1024);
        bf16x8 a2 = *(const bf16x8*)(ra + 2048);
        bf16x8 a3 = *(const bf16x8*)(ra + 3072);
        bf16x8 b0 = *(const bf16x8*)(rb);
        bf16x8 b1 = *(const bf16x8*)(rb + 1024);
        bf16x8 b2 = *(const bf16x8*)(rb + 2048);
        bf16x8 b3 = *(const bf16x8*)(rb + 3072);
        const bool st = (kt + 2) < nkt;
        if (st) STG3(so);
        __builtin_amdgcn_s_barrier();
        asm volatile("s_waitcnt lgkmcnt(0)" ::: "memory");
        __builtin_amdgcn_sched_barrier(0);
        __builtin_amdgcn_s_setprio(1);
        MMR(a0, 0); MMR(a1, 1); MMR(a2, 2); MMR(a3, 3);
        __builtin_amdgcn_s_setprio(0);
        if (st) asm volatile("s_waitcnt vmcnt(3)" ::: "memory");
        else    asm volatile("s_waitcnt vmcnt(0)" ::: "memory");
        __builtin_amdgcn_s_barrier();
        ro = (ro == 49152) ? 0 : (ro + 24576);
        so = (so == 49152) ? 0 : (so + 24576);
    }
#undef STG3
}

// ---------------------------------------------------------------------------
__global__ __launch_bounds__(256)
void convert_x_kernel(const float* __restrict__ x, bf16_t* __restrict__ xb)
{
    const size_t i = ((size_t)blockIdx.x * 256 + threadIdx.x) * 8;
    float4 a = *(const float4*)&x[i];
    float4 b = *(const float4*)&x[i + 4];
    bf16x8 o;
    o[0] = (bf16_t)a.x; o[1] = (bf16_t)a.y; o[2] = (bf16_t)a.z; o[3] = (bf16_t)a.w;
    o[4] = (bf16_t)b.x; o[5] = (bf16_t)b.y; o[6] = (bf16_t)b.z; o[7] = (bf16_t)b.w;
    *(bf16x8*)&xb[i] = o;
}

// All three W [1024x1024] fp32 -> WT bf16 transposed, z selects matrix
__global__ __launch_bounds__(256)
void transpose_w_kernel(const float* __restrict__ W0, const float* __restrict__ W1,
                        const float* __restrict__ W2, bf16_t* __restrict__ WT)
{
    __shared__ float t[32][33];
    const float* W = (blockIdx.z == 0) ? W0 : (blockIdx.z == 1) ? W1 : W2;
    bf16_t* WTz = WT + (size_t)blockIdx.z * 1024 * 1024;
    const int k0 = blockIdx.y * 32, n0 = blockIdx.x * 32;
    const int r = threadIdx.x >> 3, c4 = (threadIdx.x & 7) * 4;
    float4 v = *(const float4*)&W[(size_t)(k0 + r) * 1024 + n0 + c4];
    t[r][c4 + 0] = v.x; t[r][c4 + 1] = v.y; t[r][c4 + 2] = v.z; t[r][c4 + 3] = v.w;
    __syncthreads();
    bf16x4 o;
#pragma unroll
    for (int j = 0; j < 4; ++j) o[j] = (bf16_t)t[c4 + j][r];
    *(bf16x4*)&WTz[(size_t)(n0 + r) * 1024 + k0 + c4] = o;
}

// ---------------------------------------------------------------------------
// QK projection: C[M,2048] bf16 = xb[M,1024] x WT[2048,1024]^T + (bq|bk)
// 256x256 tiles, 256 blocks = 1/CU, bijective XCD chunking.
// ---------------------------------------------------------------------------
__global__ __launch_bounds__(512, 2)
void gemm_qk256(const bf16_t* __restrict__ A, const bf16_t* __restrict__ Bt,
                const float* __restrict__ bq, const float* __restrict__ bk,
                bf16_t* __restrict__ C, int N, int Kd)
{
    __shared__ __align__(16) char smem[98304];
    int bid = blockIdx.y * 8 + blockIdx.x;          // 256 blocks
    bid = (bid & 7) * 32 + (bid >> 3);              // XCD chunking (256%8==0)
    const int n0 = (bid & 7) * 256;
    const int m0 = (bid >> 3) * 256;
    const int tid = threadIdx.x;

    f32x4 acc[8][4];
#pragma unroll
    for (int i = 0; i < 8; ++i)
#pragma unroll
        for (int j = 0; j < 4; ++j) acc[i][j] = (f32x4)(0.0f);

    ml256x256(A + (size_t)m0 * Kd, Bt + (size_t)n0 * Kd, Kd, Kd, Kd >> 5,
              smem, tid, acc);

    const int w = tid >> 6, lane = tid & 63;
    const int wm = w & 1, wn = w >> 1, quad = lane >> 4, l16 = lane & 15;
#pragma unroll
    for (int j = 0; j < 4; ++j) {
        const int col = n0 + wn * 64 + j * 16 + l16;
        const float bval = (col < 1024) ? bq[col] : bk[col - 1024];
#pragma unroll
        for (int i = 0; i < 8; ++i) {
            const int row = m0 + wm * 128 + i * 16 + quad * 4;
#pragma unroll
            for (int r = 0; r < 4; ++r)
                C[(size_t)(row + r) * N + col] = (bf16_t)(acc[i][j][r] + bval);
        }
    }
}

// ---------------------------------------------------------------------------
// V^T projection: VT[1024, 8192] = WvT[1024,1024] x xb[8192,1024]^T + bv
// 256x128 tiles -> 4x64 = 256 blocks, XCD chunking.
// ---------------------------------------------------------------------------
__global__ __launch_bounds__(512, 2)
void gemm_vt256(const bf16_t* __restrict__ WvT, const bf16_t* __restrict__ xb,
                const float* __restrict__ bv, bf16_t* __restrict__ VT,
                int N, int Kd)
{
    __shared__ __align__(16) char smem[73728];
    int bid = blockIdx.y * 64 + blockIdx.x;         // 256 blocks
    bid = (bid & 7) * 32 + (bid >> 3);              // XCD chunking
    const int m0 = (bid >> 6) * 256;     // d
    const int n0 = (bid & 63) * 128;     // b*L + l
    const int tid = threadIdx.x;

    f32x4 acc[4][4];
#pragma unroll
    for (int i = 0; i < 4; ++i)
#pragma unroll
        for (int j = 0; j < 4; ++j) acc[i][j] = (f32x4)(0.0f);

    ml256x128(WvT + (size_t)m0 * Kd, xb + (size_t)n0 * Kd, Kd, Kd, Kd >> 5,
              smem, tid, acc);

    const int w = tid >> 6, lane = tid & 63;
    const int wm = w & 3, wn = w >> 2, quad = lane >> 4, l16 = lane & 15;
#pragma unroll
    for (int i = 0; i < 4; ++i) {
        const int row = m0 + wm * 64 + i * 16 + quad * 4;    // d index
#pragma unroll
        for (int r = 0; r < 4; ++r) {
            const float bval = bv[row + r];
#pragma unroll
            for (int j = 0; j < 4; ++j) {
                const int col = n0 + wn * 64 + j * 16 + l16;
                VT[(size_t)(row + r) * N + col] = (bf16_t)(acc[i][j][r] + bval);
            }
        }
    }
}

// ---------------------------------------------------------------------------
// Scores: 256x256 triangular tiles, 36/batch -> 144 blocks (one round, 1/CU).
// ---------------------------------------------------------------------------
__global__ __launch_bounds__(512, 2)
void scores256(const bf16_t* __restrict__ Q, const bf16_t* __restrict__ K,
               int ldq, const int* __restrict__ lengths,
               float* __restrict__ S, int L, int Dd, float alpha)
{
    __shared__ __align__(16) char smem[98304];
    const int b = blockIdx.z;
    const int len = lengths[b];
    int it = 0;
    while ((it + 1) * (it + 2) / 2 <= (int)blockIdx.x) ++it;
    const int jt = blockIdx.x - it * (it + 1) / 2;
    const int m0 = it * 256, n0 = jt * 256;
    float* Sb = S + (size_t)b * L * L;
    const int tid = threadIdx.x;

    f32x4 acc[8][4];
#pragma unroll
    for (int i = 0; i < 8; ++i)
#pragma unroll
        for (int j = 0; j < 4; ++j) acc[i][j] = (f32x4)(0.0f);

    const bf16_t* Qb = Q + (size_t)b * L * ldq + (size_t)m0 * ldq;
    const bf16_t* Kb = K + (size_t)b * L * ldq + (size_t)n0 * ldq;
    ml256x256(Qb, Kb, ldq, ldq, Dd >> 5, smem, tid, acc);

    const int w = tid >> 6, lane = tid & 63;
    const int wm = w & 1, wn = w >> 1, quad = lane >> 4, l16 = lane & 15;
#pragma unroll
    for (int i = 0; i < 8; ++i) {
#pragma unroll
        for (int j = 0; j < 4; ++j) {
            const int col = n0 + wn * 64 + j * 16 + l16;
#pragma unroll
            for (int r = 0; r < 4; ++r) {
                const int row = m0 + wm * 128 + i * 16 + quad * 4 + r;
                float s = acc[i][j][r] * alpha;
                if (col > row) s += NEGV;                 // causal first
                if (row >= len || col >= len) s += NEGV;  // then length mask
                Sb[(size_t)row * L + col] = s;
            }
        }
    }
}

// ---------------------------------------------------------------------------
// Row softmax, causally bounded: values for j<bound (128-aligned), ZEROS for
// j in [bound, bound2) with bound2 256-aligned -- pv consumes P in 256-row
// k-extents and must never read garbage.
// ---------------------------------------------------------------------------
__global__ __launch_bounds__(256)
void softmax_kernel(const float* __restrict__ S, bf16_t* __restrict__ P,
                    int L, int ldp)
{
    __shared__ float red[8];
    const int i = blockIdx.x;
    const int bound  = ((i >> 7) + 1) << 7;
    const int bound2 = ((i >> 8) + 1) << 8;
    const float* row = S + ((size_t)blockIdx.y * L + i) * L;
    bf16_t* prow = P + ((size_t)blockIdx.y * L + i) * ldp;
    const int t = threadIdx.x;
    const int w = t >> 6, lane = t & 63;
    const int j8 = t * 8;
    const bool act = j8 < bound;

    float v[8];
    float m = -3.0e38f;
    if (act) {
        float4 a = *(const float4*)&row[j8];
        float4 b = *(const float4*)&row[j8 + 4];
        v[0] = a.x; v[1] = a.y; v[2] = a.z; v[3] = a.w;
        v[4] = b.x; v[5] = b.y; v[6] = b.z; v[7] = b.w;
#pragma unroll
        for (int j = 0; j < 8; ++j) m = fmaxf(m, v[j]);
    }
#pragma unroll
    for (int off = 32; off > 0; off >>= 1) m = fmaxf(m, __shfl_down(m, off, 64));
    if (lane == 0) red[w] = m;
    __syncthreads();
    m = fmaxf(fmaxf(red[0], red[1]), fmaxf(red[2], red[3]));

    float s = 0.f;
    if (act) {
#pragma unroll
        for (int j = 0; j < 8; ++j) {
            v[j] = __expf(v[j] - m);
            s += v[j];
        }
    }
#pragma unroll
    for (int off = 32; off > 0; off >>= 1) s += __shfl_down(s, off, 64);
    if (lane == 0) red[4 + w] = s;
    __syncthreads();
    s = red[4] + red[5] + red[6] + red[7];

    if (act) {
        const float inv = 1.0f / s;
        bf16x8 o;
#pragma unroll
        for (int j = 0; j < 8; ++j) o[j] = (bf16_t)(v[j] * inv);
        *(bf16x8*)&prow[j8] = o;
    } else if (j8 < bound2) {
        bf16x8 z;
#pragma unroll
        for (int j = 0; j < 8; ++j) z[j] = (bf16_t)0.0f;
        *(bf16x8*)&prow[j8] = z;
    }
}

// ---------------------------------------------------------------------------
// PV: O[b][L,D] fp32 = P[b][L,L] x V^T (VT layout [d][b][l], ld 8192).
// 256(l) x 128(d) tiles -> 256 blocks, causal k-limit at 256-row granularity,
// heavy m-tiles first, XCD chunking within batch.
// ---------------------------------------------------------------------------
__global__ __launch_bounds__(512, 2)
void pv256(const bf16_t* __restrict__ P, int ldp,
           const bf16_t* __restrict__ VT, int ldv,
           float* __restrict__ O, int L, int Dd)
{
    __shared__ __align__(16) char smem[73728];
    const int b = blockIdx.z;
    int bid = blockIdx.y * 8 + blockIdx.x;       // 64 per batch
    bid = (bid & 7) * 8 + (bid >> 3);            // XCD chunking
    const int mt = 7 - (bid >> 3);               // heavy first
    const int m0 = mt * 256, n0 = (bid & 7) * 128;
    const int tid = threadIdx.x;

    f32x4 acc[4][4];
#pragma unroll
    for (int i = 0; i < 4; ++i)
#pragma unroll
        for (int j = 0; j < 4; ++j) acc[i][j] = (f32x4)(0.0f);

    const int nkt = (m0 + 256) >> 5;   // P[i][j]==0 for j >= roundup(i+1,256)
    const bf16_t* Pb = P + (size_t)b * L * ldp + (size_t)m0 * ldp;
    const bf16_t* Vb = VT + (size_t)b * L + (size_t)n0 * ldv;
    ml256x128(Pb, Vb, ldp, ldv, nkt, smem, tid, acc);

    float* Ob = O + (size_t)b * L * Dd;
    const int w = tid >> 6, lane = tid & 63;
    const int wm = w & 3, wn = w >> 2, quad = lane >> 4, l16 = lane & 15;
#pragma unroll
    for (int i = 0; i < 4; ++i) {
        const int row = m0 + wm * 64 + i * 16 + quad * 4;
#pragma unroll
        for (int j = 0; j < 4; ++j) {
            const int col = n0 + wn * 64 + j * 16 + l16;
#pragma unroll
            for (int r = 0; r < 4; ++r)
                Ob[(size_t)(row + r) * Dd + col] = acc[i][j][r];
        }
    }
}

// ---------------------------------------------------------------------------
extern "C" void kernel_launch(void* const* d_in, const int* in_sizes, int n_in,
                              void* d_out, int out_size, void* d_ws, size_t ws_size,
                              hipStream_t stream)
{
    const float* x  = (const float*)d_in[0];
    const float* Wq = (const float*)d_in[1];
    const float* bq = (const float*)d_in[2];
    const float* Wk = (const float*)d_in[3];
    const float* bk = (const float*)d_in[4];
    const float* Wv = (const float*)d_in[5];
    const float* bv = (const float*)d_in[6];
    const int*  len = (const int*)d_in[7];
    float* out = (float*)d_out;

    const int B = 4, L = 2048, D = 1024;
    const int M = B * L;     // 8192
    const int N2 = 2 * D;    // 2048

    // Workspace (140.5 MB):
    //  xb [8192][1024] bf16 = 16 MB
    //  WT [3072][1024] bf16 = 6 MB   (Wq^T | Wk^T | Wv^T)
    //  QK [8192][2048] bf16 = 32 MB  (cols 0:Q 1024:K; rows reused as P, ld 2048)
    //  VT [1024][8192] bf16 = 16 MB  (layout [d][b][l])
    //  S  [4][2048][2048] fp32 = 64 MB (lower-triangular tiles only)
    bf16_t* xb = (bf16_t*)d_ws;
    bf16_t* WT = xb + (size_t)M * D;
    bf16_t* QK = WT + (size_t)3 * D * D;
    bf16_t* VT = QK + (size_t)M * N2;
    float*  S  = (float*)(VT + (size_t)D * M);
    bf16_t* P  = QK;   // alias: Q,K dead after scores; ld = 2048

    // 1) x -> bf16
    convert_x_kernel<<<(M * D) / 2048, 256, 0, stream>>>(x, xb);

    // 2) all W transposes in one launch
    transpose_w_kernel<<<dim3(32, 32, 3), 256, 0, stream>>>(Wq, Wk, Wv, WT);

    // 3) QK projection (N=2048), 256x256 tiles, 256 blocks
    gemm_qk256<<<dim3(8, 32), 512, 0, stream>>>(xb, WT, bq, bk, QK, N2, D);

    // 4) V^T projection, 256x128 tiles, 256 blocks
    gemm_vt256<<<dim3(64, 4), 512, 0, stream>>>(
        WT + (size_t)2 * D * D, xb, bv, VT, M, D);

    // 5) scores, triangular 256x256 tiles, 144 blocks
    scores256<<<dim3(36, 1, B), 512, 0, stream>>>(
        QK, QK + 1024, N2, len, S, L, D, 0.03125f);

    // 6) bounded softmax -> P (aliased over QK rows), zero-filled to 256 bound
    softmax_kernel<<<dim3(L, B), 256, 0, stream>>>(S, P, L, N2);

    // 7) O = P @ V, causal k-limit, 256 blocks, heavy tiles first
    pv256<<<dim3(8, 8, 4), 512, 0, stream>>>(P, N2, VT, M, out, L, D);
}